// Round 2
// baseline (12527.232 us; speedup 1.0000x reference)
//
#include <hip/hip_runtime.h>
#include <hip/hip_fp16.h>

#define B_  16
#define T_  400
#define F_  512
#define U_  1024
#define G4_ 4096
#define BH_ (B_*U_)   // floats per (parity,dir) h buffer
#define NBLK 256

__device__ __forceinline__ unsigned bf16bits(float f) {
  unsigned u = __float_as_uint(f);
  return (u + 0x7fffu + ((u >> 16) & 1u)) >> 16;   // RNE f32->bf16
}

// ---------------- Phase 1: xw[dir] = x @ k_dir + b_dir (f16 out) ---------
__global__ __launch_bounds__(256) void gemm_xw(
    const float* __restrict__ X,
    const float* __restrict__ Kf, const float* __restrict__ Kb,
    const float* __restrict__ Bf, const float* __restrict__ Bb,
    __half* __restrict__ xwf, __half* __restrict__ xwb)
{
  const int dir = blockIdx.z;
  const float* Km   = dir ? Kb : Kf;
  const float* bias = dir ? Bb : Bf;
  __half* outp      = dir ? xwb : xwf;
  const int m0 = blockIdx.x * 64;
  const int n0 = blockIdx.y * 64;
  const int tid = threadIdx.x;
  const int tx = tid & 15, ty = tid >> 4;

  __shared__ float As[32][68];
  __shared__ float Bs[32][68];

  float acc[4][4] = {};

  for (int k0 = 0; k0 < F_; k0 += 32) {
    #pragma unroll
    for (int i = 0; i < 8; ++i) {
      int flat = i*256 + tid;
      int kk = flat & 31, m = flat >> 5;
      As[kk][m] = X[(size_t)(m0+m)*F_ + k0 + kk];
    }
    #pragma unroll
    for (int i = 0; i < 8; ++i) {
      int flat = i*256 + tid;
      int n = flat & 63, kk = flat >> 6;
      Bs[kk][n] = Km[(size_t)(k0+kk)*G4_ + n0 + n];
    }
    __syncthreads();
    #pragma unroll
    for (int kk = 0; kk < 32; ++kk) {
      float4 av = *reinterpret_cast<const float4*>(&As[kk][ty*4]);
      float4 bv = *reinterpret_cast<const float4*>(&Bs[kk][tx*4]);
      float a[4] = {av.x, av.y, av.z, av.w};
      float b[4] = {bv.x, bv.y, bv.z, bv.w};
      #pragma unroll
      for (int i = 0; i < 4; ++i)
        #pragma unroll
        for (int j = 0; j < 4; ++j)
          acc[i][j] += a[i]*b[j];
    }
    __syncthreads();
  }
  #pragma unroll
  for (int i = 0; i < 4; ++i) {
    int m = m0 + ty*4 + i;
    #pragma unroll
    for (int j = 0; j < 4; ++j) {
      int n = n0 + tx*4 + j;
      outp[(size_t)m*G4_ + n] = __float2half_rn(acc[i][j] + bias[n]);
    }
  }
}

// ---------------- manual grid barrier (monotonic counter) ----------------
__device__ __forceinline__ void gridbar(unsigned* cnt, unsigned round) {
  __syncthreads();
  if (threadIdx.x == 0) {
    __threadfence();                 // release h writes (agent scope)
    atomicAdd(cnt, 1u);
    unsigned target = NBLK * (round + 1u);
    while (__hip_atomic_load(cnt, __ATOMIC_RELAXED, __HIP_MEMORY_SCOPE_AGENT) < target)
      __builtin_amdgcn_s_sleep(1);
    __threadfence();                 // acquire
  }
  __syncthreads();
}

// ---------------- Phase 2: persistent bidirectional LSTM ----------------
// 256 WGs x 256 threads. WG -> (dir = wg>>7, u0 = (wg&127)*8), 32 gate-cols.
// LDS: r_s2 [1024 k][16 cp] packed bf16 pairs (64 KB); sbuf = h chunk / z.
__global__ __launch_bounds__(256) void lstm_rec(
    const __half* __restrict__ xwf, const __half* __restrict__ xwb,
    const float* __restrict__ Rf, const float* __restrict__ Rb,
    const float* __restrict__ gammav, const float* __restrict__ betav,
    const float* __restrict__ mmean, const float* __restrict__ mvar,
    float* __restrict__ hbuf,   // [parity(2)][dir(2)][16][1024] f32
    float* __restrict__ outp,   // [16][400][2048] f32
    unsigned* __restrict__ cnt)
{
  __shared__ unsigned r_s2[U_*16];   // 65536 B: [k][cp], lo=c0=2cp hi=c1
  __shared__ float    sbuf[16*264];  // 16896 B: h chunk [b][khalf*132+kk] / z alias

  const int wg  = blockIdx.x;
  const int dir = wg >> 7;
  const int u0  = (wg & 127) * 8;
  const __half* xw = dir ? xwb : xwf;
  const float*  R  = dir ? Rb  : Rf;
  const int tid = threadIdx.x;

  // stage R slice (bf16-packed): r_s2[k*16+cp] = pack(R[k][col(2cp)], R[k][col(2cp+1)])
  for (int i = 0; i < 64; ++i) {
    int flat = i*256 + tid;
    int k = flat >> 4, cp = flat & 15;
    int c0 = 2*cp;
    int col = (c0 >> 3)*U_ + u0 + (c0 & 7);         // gate*1024 + u0 + uu (even)
    float2 rv = *reinterpret_cast<const float2*>(&R[(size_t)k*G4_ + col]);
    r_s2[k*16 + cp] = bf16bits(rv.x) | (bf16bits(rv.y) << 16);
  }

  float inv = 0.f, add = 0.f, cst = 0.f;
  if (tid < 128) {
    int gb = tid >> 3, uu = tid & 7;
    int j = dir*U_ + u0 + uu;
    inv = gammav[j] * rsqrtf(mvar[j] + 1e-3f);
    add = betav[j] - mmean[j]*inv;
    hbuf[(size_t)(0*2 + dir)*BH_ + gb*U_ + u0 + uu] = 0.f;   // h parity 0 init
  }
  gridbar(cnt, 0);

  const int khalf = tid >> 7;
  const int bp = (tid >> 4) & 7;
  const int b0 = 2*bp, b1 = 2*bp + 1;
  const int cp = tid & 15;
  const int c0 = 2*cp, c1 = 2*cp + 1;
  const int gc0 = (c0 >> 3)*U_ + u0 + (c0 & 7);
  const int gc1 = gc0 + 1;          // c0 even -> same gate, +1
  const int kko = tid & 127;        // h staging k offset (per thread)

  for (int s = 0; s < T_; ++s) {
    const float* hin = hbuf + (size_t)((s & 1)*2 + dir)*BH_;
    const int tin = dir ? (T_ - 1 - s) : s;
    float a00 = 0.f, a01 = 0.f, a10 = 0.f, a11 = 0.f;
    if (khalf == 0) {
      const __half* x0 = xw + ((size_t)b0*T_ + tin)*G4_;
      const __half* x1 = xw + ((size_t)b1*T_ + tin)*G4_;
      a00 = __half2float(x0[gc0]); a01 = __half2float(x0[gc1]);
      a10 = __half2float(x1[gc0]); a11 = __half2float(x1[gc1]);
    }
    float hreg[16];
    #pragma unroll
    for (int i = 0; i < 16; ++i)
      hreg[i] = hin[i*U_ + khalf*512 + kko];          // chunk 0
    for (int kc = 0; kc < 4; ++kc) {
      __syncthreads();                                // sbuf free
      #pragma unroll
      for (int i = 0; i < 16; ++i)
        sbuf[i*264 + khalf*132 + kko] = hreg[i];
      __syncthreads();
      if (kc < 3) {
        #pragma unroll
        for (int i = 0; i < 16; ++i)
          hreg[i] = hin[i*U_ + khalf*512 + (kc+1)*128 + kko];
      }
      const float* h0p = &sbuf[b0*264 + khalf*132];
      const float* h1p = &sbuf[b1*264 + khalf*132];
      const unsigned* rp = &r_s2[(khalf*512 + kc*128)*16 + cp];
      #pragma unroll 4
      for (int kk = 0; kk < 128; kk += 4) {
        float4 ha = *reinterpret_cast<const float4*>(h0p + kk);
        float4 hb = *reinterpret_cast<const float4*>(h1p + kk);
        unsigned q0 = rp[(kk+0)*16];
        unsigned q1 = rp[(kk+1)*16];
        unsigned q2 = rp[(kk+2)*16];
        unsigned q3 = rp[(kk+3)*16];
        float r0l = __uint_as_float(q0 << 16), r0h = __uint_as_float(q0 & 0xffff0000u);
        float r1l = __uint_as_float(q1 << 16), r1h = __uint_as_float(q1 & 0xffff0000u);
        float r2l = __uint_as_float(q2 << 16), r2h = __uint_as_float(q2 & 0xffff0000u);
        float r3l = __uint_as_float(q3 << 16), r3h = __uint_as_float(q3 & 0xffff0000u);
        a00 += ha.x*r0l; a01 += ha.x*r0h; a10 += hb.x*r0l; a11 += hb.x*r0h;
        a00 += ha.y*r1l; a01 += ha.y*r1h; a10 += hb.y*r1l; a11 += hb.y*r1h;
        a00 += ha.z*r2l; a01 += ha.z*r2h; a10 += hb.z*r2l; a11 += hb.z*r2h;
        a00 += ha.w*r3l; a01 += ha.w*r3h; a10 += hb.w*r3l; a11 += hb.w*r3h;
      }
    }
    __syncthreads();                      // all h reads done; reuse sbuf for z
    sbuf[(khalf*16 + b0)*33 + c0] = a00;
    sbuf[(khalf*16 + b0)*33 + c1] = a01;
    sbuf[(khalf*16 + b1)*33 + c0] = a10;
    sbuf[(khalf*16 + b1)*33 + c1] = a11;
    __syncthreads();
    if (tid < 128) {
      int gb = tid >> 3, uu = tid & 7;
      float zi = sbuf[gb*33 +      uu] + sbuf[(16+gb)*33 +      uu];
      float zf = sbuf[gb*33 +  8 + uu] + sbuf[(16+gb)*33 +  8 + uu];
      float zg = sbuf[gb*33 + 16 + uu] + sbuf[(16+gb)*33 + 16 + uu];
      float zo = sbuf[gb*33 + 24 + uu] + sbuf[(16+gb)*33 + 24 + uu];
      float ig = 1.f/(1.f + __expf(-zi));
      float fg = 1.f/(1.f + __expf(-zf));
      float gg = tanhf(zg);
      float og = 1.f/(1.f + __expf(-zo));
      cst = fg*cst + ig*gg;
      float hv = og * tanhf(cst);
      hbuf[(size_t)(((s+1) & 1)*2 + dir)*BH_ + gb*U_ + u0 + uu] = hv;
      outp[((size_t)gb*T_ + tin)*2048 + dir*U_ + u0 + uu] = hv*inv + add;
    }
    gridbar(cnt, s + 1);
  }
}

extern "C" void kernel_launch(void* const* d_in, const int* in_sizes, int n_in,
                              void* d_out, int out_size, void* d_ws, size_t ws_size,
                              hipStream_t stream)
{
  const float* x  = (const float*)d_in[0];
  const float* kf = (const float*)d_in[1];
  const float* rf = (const float*)d_in[2];
  const float* bf = (const float*)d_in[3];
  const float* kb = (const float*)d_in[4];
  const float* rb = (const float*)d_in[5];
  const float* bb = (const float*)d_in[6];
  const float* ga = (const float*)d_in[7];
  const float* be = (const float*)d_in[8];
  const float* mm = (const float*)d_in[9];
  const float* mv = (const float*)d_in[10];
  float* outp = (float*)d_out;

  // ws layout: [cnt 256B][hbuf 2*2*16*1024 f32 = 256KB][xwf f16][xwb f16]
  unsigned* cnt = (unsigned*)d_ws;
  float* hbuf   = (float*)((char*)d_ws + 256);
  __half* xwf   = (__half*)((char*)d_ws + 256 + (size_t)2*2*BH_*4);
  __half* xwb   = xwf + (size_t)6400*G4_;

  hipMemsetAsync(cnt, 0, 256, stream);
  gemm_xw<<<dim3(100, 64, 2), dim3(256), 0, stream>>>(x, kf, kb, bf, bb, xwf, xwb);
  lstm_rec<<<dim3(NBLK), dim3(256), 0, stream>>>(xwf, xwb, rf, rb, ga, be, mm, mv,
                                                 hbuf, outp, cnt);
}